// Round 6
// baseline (265.661 us; speedup 1.0000x reference)
//
#include <hip/hip_runtime.h>
#include <math.h>

#define BINS 30

static constexpr int BLOCK  = 256;
static constexpr int GRID   = 1024;  // 4 resident blocks/CU (33 KiB LDS) x 256 CUs
static constexpr int SLOTS  = 32;    // 30 bins + slot 30 = trash (out-of-range), 31 pad
static constexpr int UNROLL = 8;     // float4 loads per array per superiteration

typedef float f32x4 __attribute__((ext_vector_type(4)));  // native vec: OK for nontemporal builtins

__device__ __forceinline__ float wave_sum(float v) {
    #pragma unroll
    for (int o = 32; o > 0; o >>= 1) v += __shfl_xor(v, o, 64);
    return v;
}

// Per-thread private packed histograms in LDS: h[slot*256 + tid] holds
// x-count in bits 0..15 (+1), y-count in bits 16..31 (+65536).
// ds_add_u32 fire-and-forget (no waitcnt, no RMW chain); bank = tid%32
// (conflict-free, zero same-address contention). Max x-count/thread/slot
// = 128 -> per-block column sums <= 32768 < 2^16, packed u32 sums exact.
//
// R6: UNROLL 4->8 (16 independent dwordx4 in flight per wave, 16 KiB) to
// further amortize the vmcnt drain; per-block partials written non-atomically
// to ws (g_part[block*32 + slot]) -- no global atomics, no memset node.
__global__ __launch_bounds__(BLOCK, 4) void hist_kernel(
        const float* __restrict__ x, const float* __restrict__ y,
        int n4, unsigned int* __restrict__ g_part)
{
    __shared__ unsigned int h[SLOTS * BLOCK];     // 32 KiB
    __shared__ unsigned int partial[BLOCK];       // +1 KiB
    const int tid = threadIdx.x;

    #pragma unroll
    for (int i = 0; i < SLOTS; ++i) h[i * BLOCK + tid] = 0u;
    __syncthreads();

    const f32x4* __restrict__ x4 = (const f32x4*)x;
    const f32x4* __restrict__ y4 = (const f32x4*)y;

    // torch.histc: idx = floor((v+4)*3.75) clipped to [0,29]; |v|>4 -> trash slot 30
    #define PROC(v, inc) {                                              \
        float q = ((v) + 4.0f) * 3.75f;                                 \
        int idx = (int)q;                                               \
        idx = idx > 29 ? 29 : idx;        /* v == 4.0 -> last bin */    \
        bool valid = fabsf(v) <= 4.0f;                                  \
        int slot = valid ? idx : 30;                                    \
        atomicAdd(&h[slot * BLOCK + tid], (inc));  /* ds_add_u32 */     \
    }
    #define PROC4(f, inc) { PROC((f).x, inc) PROC((f).y, inc) PROC((f).z, inc) PROC((f).w, inc) }

    const int span   = GRID * BLOCK * UNROLL;      // float4 per superiteration
    const int chunk0 = blockIdx.x * (BLOCK * UNROLL);

    for (int chunk = chunk0; chunk + BLOCK * UNROLL <= n4; chunk += span) {
        f32x4 a[UNROLL], b[UNROLL];
        #pragma unroll
        for (int j = 0; j < UNROLL; ++j)
            a[j] = __builtin_nontemporal_load(&x4[chunk + j * BLOCK + tid]);
        #pragma unroll
        for (int j = 0; j < UNROLL; ++j)
            b[j] = __builtin_nontemporal_load(&y4[chunk + j * BLOCK + tid]);
        #pragma unroll
        for (int j = 0; j < UNROLL; ++j) {
            PROC4(a[j], 1u)
            PROC4(b[j], 65536u)
        }
    }

    // Tail (empty for the benchmark's 2^23 float4s; kept for generality)
    const int tail_start = n4 - (n4 % span);
    for (int i = tail_start + blockIdx.x * BLOCK + tid; i < n4; i += GRID * BLOCK) {
        f32x4 a = x4[i], b = y4[i];
        PROC4(a, 1u)
        PROC4(b, 65536u)
    }
    #undef PROC4
    #undef PROC
    __syncthreads();

    // Reduce 256 columns per slot (packed u32 sums exact; see header comment).
    const int slot = tid & 31;
    const int c0   = (tid >> 5) * 32;
    unsigned int s = 0;
    #pragma unroll 8
    for (int c = 0; c < 32; ++c) {
        int col = c0 + ((c + tid) & 31);
        s += h[slot * BLOCK + col];
    }
    partial[tid] = s;
    __syncthreads();
    if (tid < 32) {
        unsigned int tot = 0;
        #pragma unroll
        for (int g = 0; g < 8; ++g) tot += partial[g * 32 + tid];
        g_part[blockIdx.x * 32 + tid] = tot;   // non-atomic per-block partial
    }
}

// Reduce 1024 x 32 packed partials (128 KB), then the MI epilogue.
__global__ void finalize_kernel(const unsigned int* __restrict__ g_part,
                                float* __restrict__ out)
{
    __shared__ unsigned int rsx[BLOCK], rsy[BLOCK];
    const int t    = threadIdx.x;
    const int slot = t & 31;
    const int g    = t >> 5;            // 8 groups of 32 threads

    unsigned int accx = 0, accy = 0;
    for (int b = g; b < GRID; b += 8) { // coalesced: lane k reads word b*32+k
        unsigned int p = g_part[b * 32 + slot];
        accx += p & 0xFFFFu;            // unpack BEFORE cross-block sum (overflow)
        accy += p >> 16;
    }
    rsx[t] = accx; rsy[t] = accy;
    __syncthreads();
    if (t < 32) {
        unsigned int tx = 0, ty = 0;
        #pragma unroll
        for (int k = 0; k < 8; ++k) { tx += rsx[k * 32 + slot]; ty += rsy[k * 32 + slot]; }
        rsx[slot] = tx; rsy[slot] = ty;
    }
    __syncthreads();
    if (t < 64) {                       // wave 0 does the scalar epilogue
        const bool active = t < BINS;
        float hx = active ? (float)rsx[t] : 0.0f;
        float hy = active ? (float)rsy[t] : 0.0f;
        float hj = hx + hy;             // joint = hist_x + hist_y exactly

        float Sx = wave_sum(hx);
        float Sy = wave_sum(hy);
        float Sj = wave_sum(hj);

        float px = hx / Sx;
        float py = hy / Sy;
        float jp = hj / Sj;

        // mi = 30*sum_j jp_j*(log jp_j - log py_j) - (sum_j jp_j)*(sum_i log px_i)
        float term = active ? jp * (logf(jp) - logf(py)) : 0.0f;
        float lpx  = active ? logf(px) : 0.0f;
        float sjp  = wave_sum(active ? jp : 0.0f);

        float st = wave_sum(term);
        float sl = wave_sum(lpx);
        if (t == 0) out[0] = -((float)BINS * st - sjp * sl);
    }
}

extern "C" void kernel_launch(void* const* d_in, const int* in_sizes, int n_in,
                              void* d_out, int out_size, void* d_ws, size_t ws_size,
                              hipStream_t stream) {
    const float* x = (const float*)d_in[0];
    const float* y = (const float*)d_in[1];
    const int n = in_sizes[0];               // 2^25, divisible by 4
    unsigned int* g_part = (unsigned int*)d_ws;  // GRID*32 u32 = 128 KB, fully overwritten

    hist_kernel<<<GRID, BLOCK, 0, stream>>>(x, y, n >> 2, g_part);
    finalize_kernel<<<1, BLOCK, 0, stream>>>(g_part, (float*)d_out);
}